// Round 1
// baseline (224.412 us; speedup 1.0000x reference)
//
#include <hip/hip_runtime.h>
#include <math.h>

#define DIM 192
#define OD  191          // output domain per axis (191^3)
#define TH  16
#define TW  16
#define NBH 12           // ceil(191/16)
#define CD  24           // d-planes per chunk
#define NCH 8            // ceil(191/24)

// Fused: diff -> 3x3x3 box mean -> neo-hookean energy -> mean reduction.
// One block = 16x16 (h,w) tile streaming over a chunk of d-planes.
__global__ __launch_bounds__(256)
void nh_fused_kernel(const float* __restrict__ P, float* __restrict__ out) {
    const int tid = threadIdx.x;
    const int tx  = tid & 15;        // w within tile
    const int ty  = tid >> 4;        // h within tile
    const int w0  = blockIdx.x * TW;
    const int h0  = blockIdx.y * TH;
    const int ds  = blockIdx.z * CD;
    const int de  = min(ds + CD, OD);

    // diff plane: 9 fields (dir*3+c; dir 0=H(dx),1=D(dy),2=W(dz)), 18x18 halo region
    __shared__ float sdiff[9][18][19];   // row padded to 19
    __shared__ float wsum[4];

    const int ow = w0 + tx;
    const int oh = h0 + ty;
    const bool valid = (ow < OD) && (oh < OD);

    float c0[9], c1[9], c2[9];
    #pragma unroll
    for (int f = 0; f < 9; ++f) { c1[f] = 0.f; c2[f] = 0.f; c0[f] = 0.f; }

    float acc = 0.f;

    for (int dpl = ds - 1; dpl <= de; ++dpl) {
        __syncthreads();   // protect sdiff from previous iteration's readers

        // Phase 1: build diff plane at d' = dpl over halo region [h0-1,h0+16]x[w0-1,w0+16]
        for (int l = tid; l < 18 * 18; l += 256) {
            const int hh = l / 18;
            const int ww = l - hh * 18;
            const int hp = h0 - 1 + hh;
            const int wp = w0 - 1 + ww;
            float dxv[3], dyv[3], dzv[3];
            if (dpl >= 0 && dpl < OD && hp >= 0 && hp < OD && wp >= 0 && wp < OD) {
                #pragma unroll
                for (int c = 0; c < 3; ++c) {
                    const size_t base = (((size_t)c * DIM + (size_t)dpl) * DIM + (size_t)hp) * DIM + (size_t)wp;
                    const float b  = P[base];
                    const float pd = P[base + (size_t)DIM * DIM];  // d+1
                    const float ph = P[base + DIM];                // h+1
                    const float pw = P[base + 1];                  // w+1
                    dxv[c] = fabsf(ph - b);   // diff along H
                    dyv[c] = fabsf(pd - b);   // diff along D
                    dzv[c] = fabsf(pw - b);   // diff along W
                }
            } else {
                #pragma unroll
                for (int c = 0; c < 3; ++c) { dxv[c] = 0.f; dyv[c] = 0.f; dzv[c] = 0.f; }
            }
            #pragma unroll
            for (int c = 0; c < 3; ++c) {
                sdiff[0 + c][hh][ww] = dxv[c];
                sdiff[3 + c][hh][ww] = dyv[c];
                sdiff[6 + c][hh][ww] = dzv[c];
            }
        }
        __syncthreads();

        // Phase 2: 3x3 2D window sums at this plane; rotate ring
        #pragma unroll
        for (int f = 0; f < 9; ++f) c0[f] = c1[f];
        #pragma unroll
        for (int f = 0; f < 9; ++f) c1[f] = c2[f];
        #pragma unroll
        for (int f = 0; f < 9; ++f) {
            float s = 0.f;
            #pragma unroll
            for (int j = 0; j < 3; ++j)
                #pragma unroll
                for (int k = 0; k < 3; ++k)
                    s += sdiff[f][ty + j][tx + k];
            c2[f] = s;
        }

        // Phase 3: emit output voxel at d = dpl - 1 (needs planes d-1,d,d+1)
        const int d = dpl - 1;
        if (valid && d >= ds && d < de) {
            const float inv27 = 1.f / 27.f;
            float F[9];
            #pragma unroll
            for (int f = 0; f < 9; ++f) F[f] = (c0[f] + c1[f] + c2[f]) * inv27;
            const float dydx = F[0], dxdx = F[1], dzdx = F[2];
            const float dydy = F[3], dxdy = F[4], dzdy = F[5];
            const float dydz = F[6], dxdz = F[7], dzdz = F[8];
            const float a = dxdx + 1.f, e = dydy + 1.f, iN = dzdz + 1.f;
            const float J = a * (e * iN - dydz * dzdy)
                          - dxdy * (dydx * iN - dydz * dzdx)
                          + dxdz * (dydx * dzdy - e * dzdx);
            const float Tr = a * a + dxdy * dxdy + dxdz * dxdz
                           + dydx * dydx + e * e + dydz * dydz
                           + dzdx * dzdx + dzdy * dzdy + iN * iN;
            const float stretch = Tr * expf(1.f - J) - 3.f;
            const float vol = (J - 1.f) * (J - 1.f);
            // mu=1,lam=5 -> mu'=1/6, lam'=5/(1/6+5); U = mu'/2*stretch + lam'/2*vol
            acc += 0.0833333358f * stretch + 0.4838709677f * vol;
        }
    }

    // mean scaling (191^3 < 2^24, exact in fp32)
    acc *= (1.f / 6967871.f);

    // wave reduce (64 lanes), then block reduce, one atomic per block
    #pragma unroll
    for (int off = 32; off > 0; off >>= 1) acc += __shfl_down(acc, off, 64);
    if ((tid & 63) == 0) wsum[tid >> 6] = acc;
    __syncthreads();
    if (tid == 0) {
        atomicAdd(out, wsum[0] + wsum[1] + wsum[2] + wsum[3]);
    }
}

extern "C" void kernel_launch(void* const* d_in, const int* in_sizes, int n_in,
                              void* d_out, int out_size, void* d_ws, size_t ws_size,
                              hipStream_t stream) {
    const float* y_pred = (const float*)d_in[0];
    float* out = (float*)d_out;

    // d_out is poisoned 0xAA before every timed launch — zero it (graph-capturable).
    hipMemsetAsync(out, 0, sizeof(float), stream);

    dim3 grid(NBH, NBH, NCH);
    nh_fused_kernel<<<grid, 256, 0, stream>>>(y_pred, out);
}